// Round 6
// baseline (335.105 us; speedup 1.0000x reference)
//
#include <hip/hip_runtime.h>
#include <math.h>

constexpr int Bn = 1024, DH = 2048, K1 = 4096, DO = 1024, NL = 128;
constexpr int MN = Bn * DO;  // 1M elements

typedef __bf16 bf16x8 __attribute__((ext_vector_type(8)));
typedef short  s16x8  __attribute__((ext_vector_type(8)));
typedef float  f32x4  __attribute__((ext_vector_type(4)));

__device__ __forceinline__ unsigned short f2bf(float f) {
  union { float f; unsigned u; } v; v.f = f;
  unsigned r = v.u + 0x7FFFu + ((v.u >> 16) & 1u);  // RNE
  return (unsigned short)(r >> 16);
}

// ---------- prep: concat+relu+bf16 (blocks 0..2047) and both W transposes
// (blocks 2048..3327) in ONE dispatch ----------
__global__ __launch_bounds__(256)
void prep(const float* __restrict__ sbj, const float* __restrict__ obj,
          const float* __restrict__ W1, const float* __restrict__ W2,
          unsigned short* __restrict__ Abf,
          unsigned short* __restrict__ W1t, unsigned short* __restrict__ W2t) {
  const int tid = threadIdx.x;
  if (blockIdx.x < 2048) {
    const int t = blockIdx.x * 256 + tid;
    const int m = t >> 9;
    const int k = (t & 511) << 3;
    const float* src = (k < DH) ? sbj + (size_t)m * DH + k
                                : obj + (size_t)m * DH + (k - DH);
    const float4 a = ((const float4*)src)[0];
    const float4 b = ((const float4*)src)[1];
    uint4 o;
    o.x = (unsigned)f2bf(fmaxf(a.x, 0.f)) | ((unsigned)f2bf(fmaxf(a.y, 0.f)) << 16);
    o.y = (unsigned)f2bf(fmaxf(a.z, 0.f)) | ((unsigned)f2bf(fmaxf(a.w, 0.f)) << 16);
    o.z = (unsigned)f2bf(fmaxf(b.x, 0.f)) | ((unsigned)f2bf(fmaxf(b.y, 0.f)) << 16);
    o.w = (unsigned)f2bf(fmaxf(b.z, 0.f)) | ((unsigned)f2bf(fmaxf(b.w, 0.f)) << 16);
    *(uint4*)&Abf[(size_t)m * K1 + k] = o;
    return;
  }
  __shared__ float tl[64][65];
  const int tb = blockIdx.x - 2048;
  int by = tb >> 4;
  const int c0 = (tb & 15) * 64;
  const float* in; unsigned short* out; int R;
  if (by < 64) { in = W1; out = W1t; R = K1; }
  else         { in = W2; out = W2t; R = DO; by -= 64; }
  const int r0 = by * 64;
  {
    const int rr = tid >> 4, cc = (tid & 15) * 4;
    #pragma unroll
    for (int i = 0; i < 4; ++i) {
      const float4 v = *(const float4*)&in[(size_t)(r0 + rr + i * 16) * DO + c0 + cc];
      tl[rr + i * 16][cc + 0] = v.x; tl[rr + i * 16][cc + 1] = v.y;
      tl[rr + i * 16][cc + 2] = v.z; tl[rr + i * 16][cc + 3] = v.w;
    }
  }
  __syncthreads();
  {
    const int r4 = (tid & 15) * 4;
    #pragma unroll
    for (int i = 0; i < 4; ++i) {
      const int cr = i * 16 + (tid >> 4);
      uint2 o;
      o.x = (unsigned)f2bf(tl[r4 + 0][cr]) | ((unsigned)f2bf(tl[r4 + 1][cr]) << 16);
      o.y = (unsigned)f2bf(tl[r4 + 2][cr]) | ((unsigned)f2bf(tl[r4 + 3][cr]) << 16);
      *(uint2*)&out[(size_t)(c0 + cr) * R + r0 + r4] = o;
    }
  }
}

// ---------- MFMA GEMM: 64x64 tile, 4 waves, BK=128, in-block k-split,
// block split-K. 1D grid of 1024 blocks with XCD-aware swizzle:
//   XCD = bid%8 gets a 4x2 (x,y) supertile -> per-XCD L2 working set
//   A 4 MB + B 2 MB (vs 8 MB A thrash with the naive mapping).
// Split-K tail: final reduce level + store split across waves 0 and 1. ----------
template <int KSLICE>
__global__ __launch_bounds__(256, 4)
void mfma_gemm(const unsigned short* __restrict__ A,
               const unsigned short* __restrict__ Bt,
               float* __restrict__ P, int K) {
  __shared__ __align__(16) unsigned short smem[2 * 64 * 128];  // 32 KB
  unsigned short* LA = smem;
  unsigned short* LB = smem + 64 * 128;

  const int tid = threadIdx.x;
  const int w = tid >> 6, l = tid & 63;

  // swizzled block coords: bid = g + 8*(ix + 4*iy + 32*z), g = gx + 4*gy
  const int bid = blockIdx.x;
  const int g = bid & 7, t = bid >> 3;
  const int x = (g & 3) * 4 + (t & 3);
  const int y = (g >> 2) * 8 + ((t >> 2) & 7);
  const int z = t >> 5;
  const int m0 = y * 64, n0 = x * 64;
  const int kb = z * KSLICE;

  f32x4 acc[4][4] = {};

  constexpr int NIT = KSLICE / 128;
  for (int it = 0; it < NIT; ++it) {
    const int k0 = kb + it * 128;
    #pragma unroll
    for (int i = 0; i < 4; ++i) {
      const int c = i * 256 + tid, m = c >> 4, kc = c & 15;
      const int kcg = (kc & 8) | ((kc & 7) ^ (m & 7));
      __builtin_amdgcn_global_load_lds(
          (const __attribute__((address_space(1))) unsigned int*)(A + (size_t)(m0 + m) * K + k0 + kcg * 8),
          (__attribute__((address_space(3))) unsigned int*)&LA[c * 8], 16, 0, 0);
    }
    #pragma unroll
    for (int i = 0; i < 4; ++i) {
      const int c = i * 256 + tid, n = c >> 4, kc = c & 15;
      const int kcg = (kc & 8) | ((kc & 7) ^ (n & 7));
      __builtin_amdgcn_global_load_lds(
          (const __attribute__((address_space(1))) unsigned int*)(Bt + (size_t)(n0 + n) * K + k0 + kcg * 8),
          (__attribute__((address_space(3))) unsigned int*)&LB[c * 8], 16, 0, 0);
    }
    __syncthreads();

    const int kcq = w * 4 + (l >> 4);
    bf16x8 af[4], bfr[4];
    #pragma unroll
    for (int i = 0; i < 4; ++i) {
      const int r = i * 16 + (l & 15);
      const int kca = (kcq & 8) | ((kcq & 7) ^ (r & 7));
      af[i]  = __builtin_bit_cast(bf16x8, *(const s16x8*)&LA[(r * 16 + kca) * 8]);
      bfr[i] = __builtin_bit_cast(bf16x8, *(const s16x8*)&LB[(r * 16 + kca) * 8]);
    }
    #pragma unroll
    for (int i = 0; i < 4; ++i)
      #pragma unroll
      for (int j = 0; j < 4; ++j)
        acc[i][j] = __builtin_amdgcn_mfma_f32_16x16x32_bf16(af[i], bfr[j], acc[i][j], 0, 0, 0);
    __syncthreads();
  }

  // ---- k-split reduction; last level + store distributed over waves 0,1 ----
  float* red = (float*)smem;  // 32 KB = 8192 floats
  auto writeacc = [&](float* dst, int ilo, int ihi) {
    for (int i = ilo; i < ihi; ++i)
      #pragma unroll
      for (int j = 0; j < 4; ++j)
        *(f32x4*)&dst[((i * 4 + j) * 64 + l) * 4] = acc[i][j];
  };
  auto addacc = [&](const float* src, int ilo, int ihi) {
    for (int i = ilo; i < ihi; ++i)
      #pragma unroll
      for (int j = 0; j < 4; ++j)
        acc[i][j] += *(const f32x4*)&src[((i * 4 + j) * 64 + l) * 4];
  };
  if (w >= 2) writeacc(red + (w - 2) * 4096, 0, 4);
  __syncthreads();
  if (w < 2) addacc(red + w * 4096, 0, 4);
  __syncthreads();
  // w1 publishes its i{0,1}; w0 publishes its i{2,3}  (disjoint halves of red)
  if (w == 1) writeacc(red, 0, 2);
  if (w == 0) writeacc(red, 2, 4);
  __syncthreads();
  if (w >= 2) return;
  const int ilo = (w == 0) ? 0 : 2;
  addacc(red, ilo, ilo + 2);

  float* Pz = P + (size_t)z * MN;
  for (int i = ilo; i < ilo + 2; ++i) {
    #pragma unroll
    for (int r = 0; r < 4; ++r) {
      const int m = m0 + i * 16 + (l >> 4) * 4 + r;
      #pragma unroll
      for (int j = 0; j < 4; ++j) {
        const int n = n0 + j * 16 + (l & 15);
        Pz[(size_t)m * DO + n] = acc[i][j][r];
      }
    }
  }
}

// ---------- combine: out = act(sum_z P[z] + bias) ----------
template <int KS, bool RELU, bool OUT_BF16>
__global__ __launch_bounds__(256)
void combine(const float* __restrict__ P, const float* __restrict__ bias,
             void* __restrict__ out) {
  const int row = blockIdx.x, t = threadIdx.x;
  const size_t i4 = (size_t)row * 256 + t;
  f32x4 s = ((const f32x4*)P)[i4];
  #pragma unroll
  for (int c = 1; c < KS; ++c) s += ((const f32x4*)P)[(size_t)c * (MN / 4) + i4];
  const f32x4 bb = *(const f32x4*)&bias[t * 4];
  s += bb;
  if (RELU) {
    s[0] = fmaxf(s[0], 0.f); s[1] = fmaxf(s[1], 0.f);
    s[2] = fmaxf(s[2], 0.f); s[3] = fmaxf(s[3], 0.f);
  }
  if (OUT_BF16) {
    uint2 o;
    o.x = (unsigned)f2bf(s[0]) | ((unsigned)f2bf(s[1]) << 16);
    o.y = (unsigned)f2bf(s[2]) | ((unsigned)f2bf(s[3]) << 16);
    *(uint2*)((unsigned short*)out + (size_t)row * DO + t * 4) = o;
  } else {
    *(f32x4*)((float*)out + (size_t)row * DO + t * 4) = s;
  }
}

// ---------- scores: fused (sum_z P + b2) staging + d-split partials ----------
// Block: 32 batch x 128 labels x 64-d chunk. Grid (32, 16) = 512 blocks.
__global__ __launch_bounds__(256)
void score_partial(const float* __restrict__ P, const float* __restrict__ b2,
                   const float* __restrict__ labels, float* __restrict__ SP) {
  __shared__ float es[64][33];   // [d][b]
  __shared__ float ls[64][132];  // [d][l]
  const int tid = threadIdx.x;
  const int b0 = blockIdx.x * 32;
  const int d0 = blockIdx.y * 64;

  // stage emb chunk = sum of 4 gemm2 partials + bias (E never materialized)
  #pragma unroll
  for (int i = 0; i < 2; ++i) {
    const int fi = tid + i * 256;
    const int b = fi >> 4, dq = fi & 15;
    const size_t idx = ((size_t)(b0 + b) * DO + d0 + dq * 4) / 4;
    f32x4 v = ((const f32x4*)P)[idx];
    #pragma unroll
    for (int c = 1; c < 4; ++c) v += ((const f32x4*)P)[(size_t)c * (MN / 4) + idx];
    v += *(const f32x4*)&b2[d0 + dq * 4];
    es[dq * 4 + 0][b] = v[0]; es[dq * 4 + 1][b] = v[1];
    es[dq * 4 + 2][b] = v[2]; es[dq * 4 + 3][b] = v[3];
  }
  #pragma unroll
  for (int i = 0; i < 8; ++i) {
    const int fi = tid + i * 256;
    const int lr = fi >> 4, dq = fi & 15;
    const float4 v = *(const float4*)&labels[(size_t)lr * DO + d0 + dq * 4];
    ls[dq * 4 + 0][lr] = v.x; ls[dq * 4 + 1][lr] = v.y;
    ls[dq * 4 + 2][lr] = v.z; ls[dq * 4 + 3][lr] = v.w;
  }
  __syncthreads();

  const int tb = tid & 15;   // b-pair
  const int tl = tid >> 4;   // label-octet
  float acc[2][8] = {};

  for (int dd = 0; dd < 64; ++dd) {
    const float e0 = es[dd][tb * 2 + 0];
    const float e1 = es[dd][tb * 2 + 1];
    const float4 l0 = *(const float4*)&ls[dd][tl * 8];
    const float4 l1 = *(const float4*)&ls[dd][tl * 8 + 4];
    const float lv[8] = {l0.x, l0.y, l0.z, l0.w, l1.x, l1.y, l1.z, l1.w};
    #pragma unroll
    for (int j = 0; j < 8; ++j) {
      float t0 = fmaxf(lv[j] - e0, 0.f); acc[0][j] = fmaf(t0, t0, acc[0][j]);
      float t1 = fmaxf(lv[j] - e1, 0.f); acc[1][j] = fmaf(t1, t1, acc[1][j]);
    }
  }

  float* SPz = SP + (size_t)blockIdx.y * (Bn * NL);
  #pragma unroll
  for (int i = 0; i < 2; ++i) {
    const size_t base = (size_t)(b0 + tb * 2 + i) * NL + tl * 8;
    float4 v0 = {acc[i][0], acc[i][1], acc[i][2], acc[i][3]};
    float4 v1 = {acc[i][4], acc[i][5], acc[i][6], acc[i][7]};
    *(float4*)&SPz[base]     = v0;
    *(float4*)&SPz[base + 4] = v1;
  }
}

__global__ __launch_bounds__(256)
void score_reduce(const float* __restrict__ SP, float* __restrict__ out) {
  const size_t i4 = (size_t)blockIdx.x * 256 + threadIdx.x;
  f32x4 s = ((const f32x4*)SP)[i4];
  #pragma unroll
  for (int c = 1; c < 16; ++c) s += ((const f32x4*)SP)[(size_t)c * 32768 + i4];
  f32x4 o = {-sqrtf(s[0]), -sqrtf(s[1]), -sqrtf(s[2]), -sqrtf(s[3])};
  ((f32x4*)out)[i4] = o;
}

extern "C" void kernel_launch(void* const* d_in, const int* in_sizes, int n_in,
                              void* d_out, int out_size, void* d_ws, size_t ws_size,
                              hipStream_t stream) {
  const float* sbj  = (const float*)d_in[0];
  const float* obj  = (const float*)d_in[1];
  const float* W1   = (const float*)d_in[2];
  const float* b1   = (const float*)d_in[3];
  const float* W2   = (const float*)d_in[4];
  const float* b2   = (const float*)d_in[5];
  const float* labs = (const float*)d_in[6];
  float* scores = (float*)d_out;

  char* ws = (char*)d_ws;
  // Layout (MB): Abf [0,8)  W1t [8,16)  W2t [16,18)  H [18,20)
  //              P [24,40)  SP [40,48)
  unsigned short* Abf = (unsigned short*)(ws);
  unsigned short* W1t = (unsigned short*)(ws + (8ull << 20));
  unsigned short* W2t = (unsigned short*)(ws + (16ull << 20));
  unsigned short* H   = (unsigned short*)(ws + (18ull << 20));
  float* P  = (float*)(ws + (24ull << 20));
  float* SP = (float*)(ws + (40ull << 20));

  dim3 blk(256);
  prep<<<dim3(2048 + 1280), blk, 0, stream>>>(sbj, obj, W1, W2, Abf, W1t, W2t);

  // GEMM1: K=4096, split-K=4 -> 1024 blocks (4/CU), XCD-swizzled
  mfma_gemm<1024><<<dim3(1024), blk, 0, stream>>>(Abf, W1t, P, K1);
  combine<4, true, true><<<dim3(Bn), blk, 0, stream>>>(P, b1, H);
  // GEMM2: K=1024, split-K=4 -> 1024 blocks
  mfma_gemm<256><<<dim3(1024), blk, 0, stream>>>(H, W2t, P, DO);
  // score: fused z-sum + b2 bias in staging; then d-chunk reduce
  score_partial<<<dim3(32, 16), blk, 0, stream>>>(P, b2, labs, SP);
  score_reduce<<<dim3(128), blk, 0, stream>>>(SP, scores);
}

// Round 7
// 140.989 us; speedup vs baseline: 2.3768x; 2.3768x over previous
//
#include <hip/hip_runtime.h>
#include <math.h>

constexpr int Bn = 1024, DH = 2048, K1 = 4096, DO = 1024, NL = 128;
constexpr int MN = Bn * DO;  // 1M elements

typedef __bf16 bf16x8 __attribute__((ext_vector_type(8)));
typedef short  s16x8  __attribute__((ext_vector_type(8)));
typedef float  f32x4  __attribute__((ext_vector_type(4)));

__device__ __forceinline__ unsigned short f2bf(float f) {
  union { float f; unsigned u; } v; v.f = f;
  unsigned r = v.u + 0x7FFFu + ((v.u >> 16) & 1u);  // RNE
  return (unsigned short)(r >> 16);
}

// ---------- prep: concat+relu+bf16 (blocks 0..2047) and both W transposes
// (blocks 2048..3327) in ONE dispatch ----------
__global__ __launch_bounds__(256)
void prep(const float* __restrict__ sbj, const float* __restrict__ obj,
          const float* __restrict__ W1, const float* __restrict__ W2,
          unsigned short* __restrict__ Abf,
          unsigned short* __restrict__ W1t, unsigned short* __restrict__ W2t) {
  const int tid = threadIdx.x;
  if (blockIdx.x < 2048) {
    const int t = blockIdx.x * 256 + tid;
    const int m = t >> 9;
    const int k = (t & 511) << 3;
    const float* src = (k < DH) ? sbj + (size_t)m * DH + k
                                : obj + (size_t)m * DH + (k - DH);
    const float4 a = ((const float4*)src)[0];
    const float4 b = ((const float4*)src)[1];
    uint4 o;
    o.x = (unsigned)f2bf(fmaxf(a.x, 0.f)) | ((unsigned)f2bf(fmaxf(a.y, 0.f)) << 16);
    o.y = (unsigned)f2bf(fmaxf(a.z, 0.f)) | ((unsigned)f2bf(fmaxf(a.w, 0.f)) << 16);
    o.z = (unsigned)f2bf(fmaxf(b.x, 0.f)) | ((unsigned)f2bf(fmaxf(b.y, 0.f)) << 16);
    o.w = (unsigned)f2bf(fmaxf(b.z, 0.f)) | ((unsigned)f2bf(fmaxf(b.w, 0.f)) << 16);
    *(uint4*)&Abf[(size_t)m * K1 + k] = o;
    return;
  }
  __shared__ float tl[64][65];
  const int tb = blockIdx.x - 2048;
  int by = tb >> 4;
  const int c0 = (tb & 15) * 64;
  const float* in; unsigned short* out; int R;
  if (by < 64) { in = W1; out = W1t; R = K1; }
  else         { in = W2; out = W2t; R = DO; by -= 64; }
  const int r0 = by * 64;
  {
    const int rr = tid >> 4, cc = (tid & 15) * 4;
    #pragma unroll
    for (int i = 0; i < 4; ++i) {
      const float4 v = *(const float4*)&in[(size_t)(r0 + rr + i * 16) * DO + c0 + cc];
      tl[rr + i * 16][cc + 0] = v.x; tl[rr + i * 16][cc + 1] = v.y;
      tl[rr + i * 16][cc + 2] = v.z; tl[rr + i * 16][cc + 3] = v.w;
    }
  }
  __syncthreads();
  {
    const int r4 = (tid & 15) * 4;
    #pragma unroll
    for (int i = 0; i < 4; ++i) {
      const int cr = i * 16 + (tid >> 4);
      uint2 o;
      o.x = (unsigned)f2bf(tl[r4 + 0][cr]) | ((unsigned)f2bf(tl[r4 + 1][cr]) << 16);
      o.y = (unsigned)f2bf(tl[r4 + 2][cr]) | ((unsigned)f2bf(tl[r4 + 3][cr]) << 16);
      *(uint2*)&out[(size_t)(c0 + cr) * R + r0 + r4] = o;
    }
  }
}

// ---------- MFMA GEMM: 64x64 tile, 4 waves, BK=128, in-block k-split,
// block split-K, XCD-aware 1D swizzle (XCD = bid%8 owns a 4x2 supertile).
// ALL acc indexing compile-time (runtime-indexed acc => scratch spill, r6 bug).
template <int KSLICE>
__global__ __launch_bounds__(256, 4)
void mfma_gemm(const unsigned short* __restrict__ A,
               const unsigned short* __restrict__ Bt,
               float* __restrict__ P, int K) {
  __shared__ __align__(16) unsigned short smem[2 * 64 * 128];  // 32 KB
  unsigned short* LA = smem;
  unsigned short* LB = smem + 64 * 128;

  const int tid = threadIdx.x;
  const int w = tid >> 6, l = tid & 63;

  // swizzled block coords: bid = g + 8*(ix + 4*iy + 32*z), g = gx + 4*gy
  const int bid = blockIdx.x;
  const int g = bid & 7, t = bid >> 3;
  const int x = (g & 3) * 4 + (t & 3);
  const int y = (g >> 2) * 8 + ((t >> 2) & 7);
  const int z = t >> 5;
  const int m0 = y * 64, n0 = x * 64;
  const int kb = z * KSLICE;

  f32x4 acc[4][4] = {};

  constexpr int NIT = KSLICE / 128;
  for (int it = 0; it < NIT; ++it) {
    const int k0 = kb + it * 128;
    #pragma unroll
    for (int i = 0; i < 4; ++i) {
      const int c = i * 256 + tid, m = c >> 4, kc = c & 15;
      const int kcg = (kc & 8) | ((kc & 7) ^ (m & 7));
      __builtin_amdgcn_global_load_lds(
          (const __attribute__((address_space(1))) unsigned int*)(A + (size_t)(m0 + m) * K + k0 + kcg * 8),
          (__attribute__((address_space(3))) unsigned int*)&LA[c * 8], 16, 0, 0);
    }
    #pragma unroll
    for (int i = 0; i < 4; ++i) {
      const int c = i * 256 + tid, n = c >> 4, kc = c & 15;
      const int kcg = (kc & 8) | ((kc & 7) ^ (n & 7));
      __builtin_amdgcn_global_load_lds(
          (const __attribute__((address_space(1))) unsigned int*)(Bt + (size_t)(n0 + n) * K + k0 + kcg * 8),
          (__attribute__((address_space(3))) unsigned int*)&LB[c * 8], 16, 0, 0);
    }
    __syncthreads();

    const int kcq = w * 4 + (l >> 4);
    bf16x8 af[4], bfr[4];
    #pragma unroll
    for (int i = 0; i < 4; ++i) {
      const int r = i * 16 + (l & 15);
      const int kca = (kcq & 8) | ((kcq & 7) ^ (r & 7));
      af[i]  = __builtin_bit_cast(bf16x8, *(const s16x8*)&LA[(r * 16 + kca) * 8]);
      bfr[i] = __builtin_bit_cast(bf16x8, *(const s16x8*)&LB[(r * 16 + kca) * 8]);
    }
    #pragma unroll
    for (int i = 0; i < 4; ++i)
      #pragma unroll
      for (int j = 0; j < 4; ++j)
        acc[i][j] = __builtin_amdgcn_mfma_f32_16x16x32_bf16(af[i], bfr[j], acc[i][j], 0, 0, 0);
    __syncthreads();
  }

  // ---- k-split reduction, fully unrolled (compile-time acc indices) ----
  float* red = (float*)smem;  // 8192 floats
  // level 1: waves 2,3 publish all 16 tiles
  if (w >= 2) {
    #pragma unroll
    for (int i = 0; i < 4; ++i)
      #pragma unroll
      for (int j = 0; j < 4; ++j)
        *(f32x4*)&red[(w - 2) * 4096 + ((i * 4 + j) * 64 + l) * 4] = acc[i][j];
  }
  __syncthreads();
  if (w < 2) {
    #pragma unroll
    for (int i = 0; i < 4; ++i)
      #pragma unroll
      for (int j = 0; j < 4; ++j)
        acc[i][j] += *(const f32x4*)&red[w * 4096 + ((i * 4 + j) * 64 + l) * 4];
  }
  __syncthreads();
  // level 2 (disjoint regions): w1 publishes acc i={0,1} -> red[0..2048);
  //                             w0 publishes acc i={2,3} -> red[2048..4096)
  if (w == 1) {
    #pragma unroll
    for (int i = 0; i < 2; ++i)
      #pragma unroll
      for (int j = 0; j < 4; ++j)
        *(f32x4*)&red[((i * 4 + j) * 64 + l) * 4] = acc[i][j];
  } else if (w == 0) {
    #pragma unroll
    for (int i = 0; i < 2; ++i)
      #pragma unroll
      for (int j = 0; j < 4; ++j)
        *(f32x4*)&red[2048 + ((i * 4 + j) * 64 + l) * 4] = acc[i + 2][j];
  }
  __syncthreads();
  if (w >= 2) return;

  float* Pz = P + (size_t)z * MN;
  if (w == 0) {
    // finish rows i=0,1 and store
    #pragma unroll
    for (int i = 0; i < 2; ++i) {
      #pragma unroll
      for (int j = 0; j < 4; ++j)
        acc[i][j] += *(const f32x4*)&red[((i * 4 + j) * 64 + l) * 4];
      #pragma unroll
      for (int r = 0; r < 4; ++r) {
        const int m = m0 + i * 16 + (l >> 4) * 4 + r;
        #pragma unroll
        for (int j = 0; j < 4; ++j)
          Pz[(size_t)m * DO + n0 + j * 16 + (l & 15)] = acc[i][j][r];
      }
    }
  } else {
    // w==1: finish rows i=2,3 and store
    #pragma unroll
    for (int i = 0; i < 2; ++i) {
      #pragma unroll
      for (int j = 0; j < 4; ++j)
        acc[i + 2][j] += *(const f32x4*)&red[2048 + ((i * 4 + j) * 64 + l) * 4];
      #pragma unroll
      for (int r = 0; r < 4; ++r) {
        const int m = m0 + (i + 2) * 16 + (l >> 4) * 4 + r;
        #pragma unroll
        for (int j = 0; j < 4; ++j)
          Pz[(size_t)m * DO + n0 + j * 16 + (l & 15)] = acc[i + 2][j][r];
      }
    }
  }
}

// ---------- combine: out = act(sum_z P[z] + bias) ----------
template <int KS, bool RELU, bool OUT_BF16>
__global__ __launch_bounds__(256)
void combine(const float* __restrict__ P, const float* __restrict__ bias,
             void* __restrict__ out) {
  const int row = blockIdx.x, t = threadIdx.x;
  const size_t i4 = (size_t)row * 256 + t;
  f32x4 s = ((const f32x4*)P)[i4];
  #pragma unroll
  for (int c = 1; c < KS; ++c) s += ((const f32x4*)P)[(size_t)c * (MN / 4) + i4];
  const f32x4 bb = *(const f32x4*)&bias[t * 4];
  s += bb;
  if (RELU) {
    s[0] = fmaxf(s[0], 0.f); s[1] = fmaxf(s[1], 0.f);
    s[2] = fmaxf(s[2], 0.f); s[3] = fmaxf(s[3], 0.f);
  }
  if (OUT_BF16) {
    uint2 o;
    o.x = (unsigned)f2bf(s[0]) | ((unsigned)f2bf(s[1]) << 16);
    o.y = (unsigned)f2bf(s[2]) | ((unsigned)f2bf(s[3]) << 16);
    *(uint2*)((unsigned short*)out + (size_t)row * DO + t * 4) = o;
  } else {
    *(f32x4*)((float*)out + (size_t)row * DO + t * 4) = s;
  }
}

// ---------- scores: fused (sum_z P + b2) staging + d-split partials ----------
__global__ __launch_bounds__(256)
void score_partial(const float* __restrict__ P, const float* __restrict__ b2,
                   const float* __restrict__ labels, float* __restrict__ SP) {
  __shared__ float es[64][33];   // [d][b]
  __shared__ float ls[64][132];  // [d][l]
  const int tid = threadIdx.x;
  const int b0 = blockIdx.x * 32;
  const int d0 = blockIdx.y * 64;

  // stage emb chunk = sum of 4 gemm2 partials + bias (E never materialized)
  #pragma unroll
  for (int i = 0; i < 2; ++i) {
    const int fi = tid + i * 256;
    const int b = fi >> 4, dq = fi & 15;
    const size_t idx = ((size_t)(b0 + b) * DO + d0 + dq * 4) / 4;
    f32x4 v = ((const f32x4*)P)[idx];
    #pragma unroll
    for (int c = 1; c < 4; ++c) v += ((const f32x4*)P)[(size_t)c * (MN / 4) + idx];
    v += *(const f32x4*)&b2[d0 + dq * 4];
    es[dq * 4 + 0][b] = v[0]; es[dq * 4 + 1][b] = v[1];
    es[dq * 4 + 2][b] = v[2]; es[dq * 4 + 3][b] = v[3];
  }
  #pragma unroll
  for (int i = 0; i < 8; ++i) {
    const int fi = tid + i * 256;
    const int lr = fi >> 4, dq = fi & 15;
    const float4 v = *(const float4*)&labels[(size_t)lr * DO + d0 + dq * 4];
    ls[dq * 4 + 0][lr] = v.x; ls[dq * 4 + 1][lr] = v.y;
    ls[dq * 4 + 2][lr] = v.z; ls[dq * 4 + 3][lr] = v.w;
  }
  __syncthreads();

  const int tb = tid & 15;   // b-pair
  const int tl = tid >> 4;   // label-octet
  float acc[2][8] = {};

  for (int dd = 0; dd < 64; ++dd) {
    const float e0 = es[dd][tb * 2 + 0];
    const float e1 = es[dd][tb * 2 + 1];
    const float4 l0 = *(const float4*)&ls[dd][tl * 8];
    const float4 l1 = *(const float4*)&ls[dd][tl * 8 + 4];
    const float lv[8] = {l0.x, l0.y, l0.z, l0.w, l1.x, l1.y, l1.z, l1.w};
    #pragma unroll
    for (int j = 0; j < 8; ++j) {
      float t0 = fmaxf(lv[j] - e0, 0.f); acc[0][j] = fmaf(t0, t0, acc[0][j]);
      float t1 = fmaxf(lv[j] - e1, 0.f); acc[1][j] = fmaf(t1, t1, acc[1][j]);
    }
  }

  float* SPz = SP + (size_t)blockIdx.y * (Bn * NL);
  #pragma unroll
  for (int i = 0; i < 2; ++i) {
    const size_t base = (size_t)(b0 + tb * 2 + i) * NL + tl * 8;
    float4 v0 = {acc[i][0], acc[i][1], acc[i][2], acc[i][3]};
    float4 v1 = {acc[i][4], acc[i][5], acc[i][6], acc[i][7]};
    *(float4*)&SPz[base]     = v0;
    *(float4*)&SPz[base + 4] = v1;
  }
}

__global__ __launch_bounds__(256)
void score_reduce(const float* __restrict__ SP, float* __restrict__ out) {
  const size_t i4 = (size_t)blockIdx.x * 256 + threadIdx.x;
  f32x4 s = ((const f32x4*)SP)[i4];
  #pragma unroll
  for (int c = 1; c < 16; ++c) s += ((const f32x4*)SP)[(size_t)c * 32768 + i4];
  f32x4 o = {-sqrtf(s[0]), -sqrtf(s[1]), -sqrtf(s[2]), -sqrtf(s[3])};
  ((f32x4*)out)[i4] = o;
}

extern "C" void kernel_launch(void* const* d_in, const int* in_sizes, int n_in,
                              void* d_out, int out_size, void* d_ws, size_t ws_size,
                              hipStream_t stream) {
  const float* sbj  = (const float*)d_in[0];
  const float* obj  = (const float*)d_in[1];
  const float* W1   = (const float*)d_in[2];
  const float* b1   = (const float*)d_in[3];
  const float* W2   = (const float*)d_in[4];
  const float* b2   = (const float*)d_in[5];
  const float* labs = (const float*)d_in[6];
  float* scores = (float*)d_out;

  char* ws = (char*)d_ws;
  // Layout (MB): Abf [0,8)  W1t [8,16)  W2t [16,18)  H [18,20)
  //              P [24,40)  SP [40,48)
  unsigned short* Abf = (unsigned short*)(ws);
  unsigned short* W1t = (unsigned short*)(ws + (8ull << 20));
  unsigned short* W2t = (unsigned short*)(ws + (16ull << 20));
  unsigned short* H   = (unsigned short*)(ws + (18ull << 20));
  float* P  = (float*)(ws + (24ull << 20));
  float* SP = (float*)(ws + (40ull << 20));

  dim3 blk(256);
  prep<<<dim3(2048 + 1280), blk, 0, stream>>>(sbj, obj, W1, W2, Abf, W1t, W2t);

  // GEMM1: K=4096, split-K=4 -> 1024 blocks (4/CU), XCD-swizzled
  mfma_gemm<1024><<<dim3(1024), blk, 0, stream>>>(Abf, W1t, P, K1);
  combine<4, true, true><<<dim3(Bn), blk, 0, stream>>>(P, b1, H);
  // GEMM2: K=1024, split-K=4 -> 1024 blocks
  mfma_gemm<256><<<dim3(1024), blk, 0, stream>>>(H, W2t, P, DO);
  // score: fused z-sum + b2 bias in staging; then d-chunk reduce
  score_partial<<<dim3(32, 16), blk, 0, stream>>>(P, b2, labs, SP);
  score_reduce<<<dim3(128), blk, 0, stream>>>(SP, scores);
}